// Round 1
// baseline (818.507 us; speedup 1.0000x reference)
//
#include <hip/hip_runtime.h>

typedef unsigned short u16;
typedef __attribute__((ext_vector_type(8))) short short8;
typedef __attribute__((ext_vector_type(4))) float f32x4;
typedef __attribute__((ext_vector_type(4))) unsigned short u16x4;

#define NN 262144
#define CC 256
#define RR 64
#define GG 1024

// ws layout (bytes):
//   0        : 6 bf16 weight matrices, 16384 elems each (w1g,w2g,w1l,w2l,w1a,w2a) = 196608 B
//   196608   : seg float [1024][256] = 1048576 B
//   1245184  : cnt int [1024] = 4096 B

static __device__ __forceinline__ u16 f2bf(float f) {
  unsigned u = __builtin_bit_cast(unsigned, f);
  u += 0x7fffu + ((u >> 16) & 1u);   // RNE to bf16
  return (u16)(u >> 16);
}

// v_cvt_pk_bf16_f32: D[15:0]=bf16(lo), D[31:16]=bf16(hi), RNE. One VALU instr
// replaces ~8-10 for the manual bit-twiddle pair.
static __device__ __forceinline__ unsigned cvt_pk_bf16(float lo, float hi) {
  unsigned r;
  asm("v_cvt_pk_bf16_f32 %0, %1, %2" : "=v"(r) : "v"(lo), "v"(hi));
  return r;
}

static __device__ __forceinline__ void lgkm0() {
  __asm__ volatile("s_waitcnt lgkmcnt(0)" ::: "memory");
}

static __device__ __forceinline__ short8 pack8(f32x4 a, f32x4 b) {
  union { unsigned u[4]; short8 s; } r;
  r.u[0] = cvt_pk_bf16(a[0], a[1]);
  r.u[1] = cvt_pk_bf16(a[2], a[3]);
  r.u[2] = cvt_pk_bf16(b[0], b[1]);
  r.u[3] = cvt_pk_bf16(b[2], b[3]);
  return r.s;
}

static __device__ __forceinline__ u16x4 pack4(float v0, float v1, float v2, float v3) {
  union { unsigned u[2]; u16x4 s; } r;
  r.u[0] = cvt_pk_bf16(v0, v1);
  r.u[1] = cvt_pk_bf16(v2, v3);
  return r.s;
}

#define MFMA16(a, b, c) __builtin_amdgcn_mfma_f32_16x16x32_bf16((a), (b), (c), 0, 0, 0)

// ---- weight fp32 -> bf16 conversion (96 blocks x 256 thr x 4 elems = 6*16384) ----
__global__ void k_cvt(const float* __restrict__ a0, const float* __restrict__ a1,
                      const float* __restrict__ a2, const float* __restrict__ a3,
                      const float* __restrict__ a4, const float* __restrict__ a5,
                      u16* __restrict__ dst) {
  int m = blockIdx.x >> 4;
  const float* s = (m == 0) ? a0 : (m == 1) ? a1 : (m == 2) ? a2
                 : (m == 3) ? a3 : (m == 4) ? a4 : a5;
  int off = (((blockIdx.x & 15) << 8) | threadIdx.x) << 2;
  f32x4 v = *(const f32x4*)(s + off);
  u16x4 p;
  p[0] = f2bf(v[0]); p[1] = f2bf(v[1]); p[2] = f2bf(v[2]); p[3] = f2bf(v[3]);
  *(u16x4*)(dst + m * 16384 + off) = p;
}

// ---- K1: glb MLP + segment sums/counts. 1 wave = 16 nodes. ----
// Per-wave LDS buffer: z stage (16 x 72 bf16 = 2304 B) time-shared with
// g slab stage (16 x 68 f32 = 4352 B); + 16 ints of batch_idx.
#define K1_WB 4416
__global__ __launch_bounds__(256) void k_glb(
    const float* __restrict__ x, const u16* __restrict__ wbf,
    const int* __restrict__ bidx, const float* __restrict__ pa,
    float* __restrict__ seg, int* __restrict__ cnt) {
  __shared__ char smem[4 * K1_WB];
  const int tid = threadIdx.x;
  const int wave = tid >> 6, lane = tid & 63;
  const int low = lane & 15, quad = lane >> 4;
  char* mybuf = smem + wave * K1_WB;
  u16* zb = (u16*)mybuf;            // stride 72 bf16 (144 B rows, 16B aligned)
  float* gs = (float*)mybuf;        // stride 68 f32 (272 B rows, 16B aligned)
  int* lb = (int*)(mybuf + 4352);   // 16 ints
  const int tile = (blockIdx.x << 2) + wave;
  const int node0 = tile << 4;
  const float alpha = pa[0];
  const u16* w1 = wbf;              // glb_w1 [64][256]
  const u16* w2 = wbf + 16384;      // glb_w2 [256][64]

  if (lane < 16) lb[lane] = bidx[node0 + lane];

  // layer1: Z^T = W1 * X^T   (M=64 -> 4 mtiles, K=256 -> 8 ksteps)
  f32x4 z[4] = {};
  const float* xrow = x + (size_t)(node0 + low) * CC;
#pragma unroll
  for (int ks = 0; ks < 8; ks++) {
    const float* xp = xrow + ks * 32 + quad * 8;
    short8 xb = pack8(*(const f32x4*)xp, *(const f32x4*)(xp + 4));
#pragma unroll
    for (int mt = 0; mt < 4; mt++) {
      short8 wa = *(const short8*)(w1 + (mt * 16 + low) * CC + ks * 32 + quad * 8);
      z[mt] = MFMA16(wa, xb, z[mt]);
    }
  }
  // PReLU + stage z (lane holds z[node=low][r=mt*16+quad*4+reg])
#pragma unroll
  for (int mt = 0; mt < 4; mt++) {
    float v0 = z[mt][0], v1 = z[mt][1], v2 = z[mt][2], v3 = z[mt][3];
    v0 = v0 >= 0.f ? v0 : alpha * v0;
    v1 = v1 >= 0.f ? v1 : alpha * v1;
    v2 = v2 >= 0.f ? v2 : alpha * v2;
    v3 = v3 >= 0.f ? v3 : alpha * v3;
    *(u16x4*)(zb + low * 72 + mt * 16 + quad * 4) = pack4(v0, v1, v2, v3);
  }
  lgkm0();
  // layer2: G^T = W2 * Z^T   (M=256 -> 16 mtiles, K=64 -> 2 ksteps)
  f32x4 g[16] = {};
#pragma unroll
  for (int ks = 0; ks < 2; ks++) {
    short8 zf = *(const short8*)(zb + low * 72 + ks * 32 + quad * 8);
#pragma unroll
    for (int mt = 0; mt < 16; mt++) {
      short8 wa = *(const short8*)(w2 + (mt * 16 + low) * RR + ks * 32 + quad * 8);
      g[mt] = MFMA16(wa, zf, g[mt]);
    }
  }
  lgkm0();  // z reads drained before buffer reuse

  // node counts per graph (once per tile; batch_idx sorted -> run-length)
  if (lane == 0) {
    int cur = lb[0], rl = 0;
#pragma unroll
    for (int n = 0; n < 16; n++) {
      int b = lb[n];
      if (b != cur) { atomicAdd(cnt + cur, rl); rl = 0; cur = b; }
      rl++;
    }
    atomicAdd(cnt + cur, rl);
  }

  // segment reduce: 4 slabs of 64 cols, run-length flush (uniform branches)
#pragma unroll
  for (int slab = 0; slab < 4; slab++) {
#pragma unroll
    for (int mt2 = 0; mt2 < 4; mt2++)
      *(f32x4*)(gs + low * 68 + mt2 * 16 + quad * 4) = g[slab * 4 + mt2];
    lgkm0();
    float acc = 0.f;
    int cur = lb[0];
#pragma unroll
    for (int n = 0; n < 16; n++) {
      int b = lb[n];
      if (b != cur) {
        atomicAdd(seg + (size_t)cur * CC + slab * 64 + lane, acc);
        acc = 0.f; cur = b;
      }
      acc += gs[n * 68 + lane];
    }
    atomicAdd(seg + (size_t)cur * CC + slab * 64 + lane, acc);
    lgkm0();  // reads drained before next slab overwrite
  }
}

// ---- K2: seg -> seg_mean ----
__global__ __launch_bounds__(256) void k_norm(float* __restrict__ seg,
                                              const int* __restrict__ cnt) {
  int g = blockIdx.x;
  int c = cnt[g];
  float s = (c > 0) ? (1.0f / (float)c) : 0.0f;
  seg[(size_t)g * CC + threadIdx.x] *= s;
}

// ---- K3: local MLP + gather + attn MLP + sigmoid. 1 wave = 16 nodes. ----
// Per-wave LDS: h stage 16 x 264 bf16 = 8448 B; z (stride 72) and out-slab
// (stride 68 f32) time-share the same region.
#define K3_WB 8448
__global__ __launch_bounds__(256) void k_attn(
    const float* __restrict__ x, const u16* __restrict__ wbf,
    const int* __restrict__ bidx, const float* __restrict__ seg,
    const float* __restrict__ pal, const float* __restrict__ paa,
    float* __restrict__ out) {
  __shared__ char smem[4 * K3_WB];
  const int tid = threadIdx.x;
  const int wave = tid >> 6, lane = tid & 63;
  const int low = lane & 15, quad = lane >> 4;
  char* mybuf = smem + wave * K3_WB;
  u16* hb = (u16*)mybuf;      // stride 264 bf16 (528 B rows, 16B aligned)
  u16* zb = (u16*)mybuf;      // stride 72 bf16
  float* gs = (float*)mybuf;  // stride 68 f32
  const int tile = (blockIdx.x << 2) + wave;
  const int node0 = tile << 4;
  const float al = pal[0], aa = paa[0];
  const u16* w1l = wbf + 2 * 16384;
  const u16* w2l = wbf + 3 * 16384;
  const u16* w1a = wbf + 4 * 16384;
  const u16* w2a = wbf + 5 * 16384;

  // ---- local MLP layer1 ----
  f32x4 z[4] = {};
  const float* xrow = x + (size_t)(node0 + low) * CC;
#pragma unroll
  for (int ks = 0; ks < 8; ks++) {
    const float* xp = xrow + ks * 32 + quad * 8;
    short8 xb = pack8(*(const f32x4*)xp, *(const f32x4*)(xp + 4));
#pragma unroll
    for (int mt = 0; mt < 4; mt++) {
      short8 wa = *(const short8*)(w1l + (mt * 16 + low) * CC + ks * 32 + quad * 8);
      z[mt] = MFMA16(wa, xb, z[mt]);
    }
  }
#pragma unroll
  for (int mt = 0; mt < 4; mt++) {
    float v0 = z[mt][0], v1 = z[mt][1], v2 = z[mt][2], v3 = z[mt][3];
    v0 = v0 >= 0.f ? v0 : al * v0;
    v1 = v1 >= 0.f ? v1 : al * v1;
    v2 = v2 >= 0.f ? v2 : al * v2;
    v3 = v3 >= 0.f ? v3 : al * v3;
    *(u16x4*)(zb + low * 72 + mt * 16 + quad * 4) = pack4(v0, v1, v2, v3);
  }
  lgkm0();
  // ---- local MLP layer2 -> loc accs ----
  f32x4 loc[16] = {};
#pragma unroll
  for (int ks = 0; ks < 2; ks++) {
    short8 zf = *(const short8*)(zb + low * 72 + ks * 32 + quad * 8);
#pragma unroll
    for (int mt = 0; mt < 16; mt++) {
      short8 wa = *(const short8*)(w2l + (mt * 16 + low) * RR + ks * 32 + quad * 8);
      loc[mt] = MFMA16(wa, zf, loc[mt]);
    }
  }
  lgkm0();  // z reads drained before h writes reuse region

  // ---- h = loc + seg_mean[batch_idx[node]]  (stage as bf16) ----
  const int myb = bidx[node0 + low];
  const float* srow = seg + (size_t)myb * CC;
#pragma unroll
  for (int mt = 0; mt < 16; mt++) {
    f32x4 sv = *(const f32x4*)(srow + mt * 16 + quad * 4);
    *(u16x4*)(hb + low * 264 + mt * 16 + quad * 4) =
        pack4(loc[mt][0] + sv[0], loc[mt][1] + sv[1],
              loc[mt][2] + sv[2], loc[mt][3] + sv[3]);
  }
  lgkm0();

  // ---- attn MLP layer1 (B-frags straight from staged h) ----
  f32x4 z2[4] = {};
#pragma unroll
  for (int ks = 0; ks < 8; ks++) {
    short8 hf = *(const short8*)(hb + low * 264 + ks * 32 + quad * 8);
#pragma unroll
    for (int mt = 0; mt < 4; mt++) {
      short8 wa = *(const short8*)(w1a + (mt * 16 + low) * CC + ks * 32 + quad * 8);
      z2[mt] = MFMA16(wa, hf, z2[mt]);
    }
  }
  lgkm0();  // h reads drained before z2 stage overwrites region
#pragma unroll
  for (int mt = 0; mt < 4; mt++) {
    float v0 = z2[mt][0], v1 = z2[mt][1], v2 = z2[mt][2], v3 = z2[mt][3];
    v0 = v0 >= 0.f ? v0 : aa * v0;
    v1 = v1 >= 0.f ? v1 : aa * v1;
    v2 = v2 >= 0.f ? v2 : aa * v2;
    v3 = v3 >= 0.f ? v3 : aa * v3;
    *(u16x4*)(zb + low * 72 + mt * 16 + quad * 4) = pack4(v0, v1, v2, v3);
  }
  lgkm0();
  // ---- attn MLP layer2 ----
  f32x4 o[16] = {};
#pragma unroll
  for (int ks = 0; ks < 2; ks++) {
    short8 zf = *(const short8*)(zb + low * 72 + ks * 32 + quad * 8);
#pragma unroll
    for (int mt = 0; mt < 16; mt++) {
      short8 wa = *(const short8*)(w2a + (mt * 16 + low) * RR + ks * 32 + quad * 8);
      o[mt] = MFMA16(wa, zf, o[mt]);
    }
  }
  // sigmoid: v_exp + v_rcp (1 ulp rcp; avoids the ~10-instr IEEE div sequence)
#pragma unroll
  for (int mt = 0; mt < 16; mt++)
#pragma unroll
    for (int i = 0; i < 4; i++)
      o[mt][i] = __builtin_amdgcn_rcpf(1.0f + __expf(-o[mt][i]));
  lgkm0();  // z reads drained before slab writes

  // ---- coalesced store via 64-col LDS slabs ----
#pragma unroll
  for (int slab = 0; slab < 4; slab++) {
#pragma unroll
    for (int mt2 = 0; mt2 < 4; mt2++)
      *(f32x4*)(gs + low * 68 + mt2 * 16 + quad * 4) = o[slab * 4 + mt2];
    lgkm0();
#pragma unroll
    for (int n = 0; n < 16; n++)
      out[(size_t)(node0 + n) * CC + slab * 64 + lane] = gs[n * 68 + lane];
    lgkm0();
  }
}

extern "C" void kernel_launch(void* const* d_in, const int* in_sizes, int n_in,
                              void* d_out, int out_size, void* d_ws, size_t ws_size,
                              hipStream_t stream) {
  (void)in_sizes; (void)n_in; (void)out_size; (void)ws_size;
  const float* x   = (const float*)d_in[0];
  const float* w1g = (const float*)d_in[1];
  const float* ag  = (const float*)d_in[2];
  const float* w2g = (const float*)d_in[3];
  const float* w1l = (const float*)d_in[4];
  const float* al  = (const float*)d_in[5];
  const float* w2l = (const float*)d_in[6];
  const float* w1a = (const float*)d_in[7];
  const float* aa  = (const float*)d_in[8];
  const float* w2a = (const float*)d_in[9];
  const int* bidx  = (const int*)d_in[10];
  float* out = (float*)d_out;

  u16* wbf   = (u16*)d_ws;
  float* seg = (float*)((char*)d_ws + 196608);
  int* cnt   = (int*)((char*)d_ws + 196608 + 1048576);

  hipMemsetAsync(seg, 0, 1048576 + 4096, stream);
  k_cvt<<<96, 256, 0, stream>>>(w1g, w2g, w1l, w2l, w1a, w2a, wbf);
  k_glb<<<NN / 64, 256, 0, stream>>>(x, wbf, bidx, ag, seg, cnt);
  k_norm<<<GG, 256, 0, stream>>>(seg, cnt);
  k_attn<<<NN / 64, 256, 0, stream>>>(x, wbf, bidx, seg, al, aa, out);
}

// Round 2
// 649.445 us; speedup vs baseline: 1.2603x; 1.2603x over previous
//
#include <hip/hip_runtime.h>

typedef unsigned short u16;
typedef __attribute__((ext_vector_type(8))) short short8;
typedef __attribute__((ext_vector_type(4))) float f32x4;
typedef __attribute__((ext_vector_type(4))) unsigned short u16x4;
typedef __attribute__((ext_vector_type(2))) unsigned u32x2;

#define NN 262144
#define CC 256
#define RR 64
#define GG 1024

// LDS byte-offset swizzle for row-major [node][feat] bf16 tiles: XOR node low
// bits into the 16B-slot bits -> 2-way max bank aliasing on ds_read_b128 (free).
#define SWZ(b, n) ((b) ^ (((n) & 7) << 4))

// ws layout (bytes):
//   0        : 6 bf16 weight matrices, 16384 elems each (w1g,w2g,w1l,w2l,w1a,w2a)
//   196608   : seg float [1024][256]
//   1245184  : cnt int [1024]

static __device__ __forceinline__ u16 f2bf(float f) {
  unsigned u = __builtin_bit_cast(unsigned, f);
  u += 0x7fffu + ((u >> 16) & 1u);   // RNE to bf16
  return (u16)(u >> 16);
}

// v_cvt_pk_bf16_f32: D[15:0]=bf16(lo), D[31:16]=bf16(hi), RNE.
static __device__ __forceinline__ unsigned cvt_pk_bf16(float lo, float hi) {
  unsigned r;
  asm("v_cvt_pk_bf16_f32 %0, %1, %2" : "=v"(r) : "v"(lo), "v"(hi));
  return r;
}

static __device__ __forceinline__ void lgkm0() {
  __asm__ volatile("s_waitcnt lgkmcnt(0)" ::: "memory");
}

#define MFMA16(a, b, c) __builtin_amdgcn_mfma_f32_16x16x32_bf16((a), (b), (c), 0, 0, 0)

// ---- weight fp32 -> bf16 conversion ----
__global__ void k_cvt(const float* __restrict__ a0, const float* __restrict__ a1,
                      const float* __restrict__ a2, const float* __restrict__ a3,
                      const float* __restrict__ a4, const float* __restrict__ a5,
                      u16* __restrict__ dst) {
  int m = blockIdx.x >> 4;
  const float* s = (m == 0) ? a0 : (m == 1) ? a1 : (m == 2) ? a2
                 : (m == 3) ? a3 : (m == 4) ? a4 : a5;
  int off = (((blockIdx.x & 15) << 8) | threadIdx.x) << 2;
  f32x4 v = *(const f32x4*)(s + off);
  u16x4 p;
  p[0] = f2bf(v[0]); p[1] = f2bf(v[1]); p[2] = f2bf(v[2]); p[3] = f2bf(v[3]);
  *(u16x4*)(dst + m * 16384 + off) = p;
}

// ============================================================================
// Block = 64 nodes, 4 waves. Feature-split: wave w computes feature slab
// [w*16..] (layer1) / [w*64..] (layer2) for ALL 64 nodes. x staged once in LDS
// as swizzled bf16; z/h exchanged via LDS. Per-block global weight traffic =
// 32 KB/matrix (was 128 KB), each weight frag feeds 4 independent MFMAs.
// LDS regions: XB 0..32768 (x/h [64][256] bf16, later 4x 4352B f32 slabs),
//              ZB 32768..40960 (z [64][64] bf16), LB 40960 (k_glb only, 64 int)
// ============================================================================
#define ZBOFF 32768

// ---- K1: glb MLP + segment sums/counts ----
__global__ __launch_bounds__(256, 3) void k_glb(
    const float* __restrict__ x, const u16* __restrict__ wbf,
    const int* __restrict__ bidx, const float* __restrict__ pa,
    float* __restrict__ seg, int* __restrict__ cnt) {
  __shared__ __align__(16) char smem[41216];
  const int tid = threadIdx.x;
  const int wave = tid >> 6, lane = tid & 63;
  const int low = lane & 15, quad = lane >> 4;
  const int node0 = blockIdx.x << 6;
  const float alpha = pa[0];
  const u16* w1 = wbf;              // glb_w1 [64][256]
  const u16* w2 = wbf + 16384;      // glb_w2 [256][64]
  int* lbp = (int*)(smem + 40960);

  if (tid < 64) lbp[tid] = bidx[node0 + tid];

  // ---- stage x -> swizzled bf16 [64][256] ----
  const float* xsrc = x + (size_t)node0 * CC;
#pragma unroll
  for (int k = 0; k < 16; k++) {
    int f = k * 1024 + tid * 4;
    f32x4 v = *(const f32x4*)(xsrc + f);
    int node = f >> 8;
    u32x2 p;
    p[0] = cvt_pk_bf16(v[0], v[1]);
    p[1] = cvt_pk_bf16(v[2], v[3]);
    *(u32x2*)(smem + SWZ(node * 512 + (f & 255) * 2, node)) = p;
  }
  __syncthreads();

  // ---- layer1: wave's 16 feats x all 64 nodes ----
  f32x4 z[4] = {};
  const u16* w1p = w1 + (wave * 16 + low) * CC;
#pragma unroll
  for (int ks = 0; ks < 8; ks++) {
    short8 wa = *(const short8*)(w1p + ks * 32 + quad * 8);
#pragma unroll
    for (int nt = 0; nt < 4; nt++) {
      int node = nt * 16 + low;
      short8 xf = *(const short8*)(smem + SWZ(node * 512 + ks * 64 + quad * 16, node));
      z[nt] = MFMA16(wa, xf, z[nt]);
    }
  }
  // PReLU + stage z [64][64] bf16
#pragma unroll
  for (int nt = 0; nt < 4; nt++) {
    float v0 = z[nt][0], v1 = z[nt][1], v2 = z[nt][2], v3 = z[nt][3];
    v0 = v0 >= 0.f ? v0 : alpha * v0;
    v1 = v1 >= 0.f ? v1 : alpha * v1;
    v2 = v2 >= 0.f ? v2 : alpha * v2;
    v3 = v3 >= 0.f ? v3 : alpha * v3;
    int node = nt * 16 + low;
    u32x2 p;
    p[0] = cvt_pk_bf16(v0, v1);
    p[1] = cvt_pk_bf16(v2, v3);
    *(u32x2*)(smem + ZBOFF + SWZ(node * 128 + wave * 32 + quad * 8, node)) = p;
  }
  __syncthreads();

  // node counts (per-wave 16-node chunk, run-length on sorted bidx)
  if (lane == 0) {
    int base = wave * 16;
    int cur = lbp[base], rl = 0;
#pragma unroll
    for (int n = 0; n < 16; n++) {
      int b = lbp[base + n];
      if (b != cur) { atomicAdd(cnt + cur, rl); rl = 0; cur = b; }
      rl++;
    }
    atomicAdd(cnt + cur, rl);
  }

  // ---- layer2: wave's 64 feats x all 64 nodes ----
  f32x4 g[4][4] = {};   // [nt][mt]
#pragma unroll
  for (int ks2 = 0; ks2 < 2; ks2++) {
    short8 zf[4];
#pragma unroll
    for (int nt = 0; nt < 4; nt++) {
      int node = nt * 16 + low;
      zf[nt] = *(const short8*)(smem + ZBOFF + SWZ(node * 128 + ks2 * 64 + quad * 16, node));
    }
#pragma unroll
    for (int mt = 0; mt < 4; mt++) {
      short8 wa = *(const short8*)(w2 + (wave * 64 + mt * 16 + low) * RR + ks2 * 32 + quad * 8);
#pragma unroll
      for (int nt = 0; nt < 4; nt++)
        g[nt][mt] = MFMA16(wa, zf[nt], g[nt][mt]);
    }
  }
  lgkm0();

  // ---- segment reduce: per nt-tile, stage [16][68] f32 slab, run-length flush ----
  float* slab = (float*)(smem + wave * 4352);
#pragma unroll
  for (int nt = 0; nt < 4; nt++) {
#pragma unroll
    for (int mt = 0; mt < 4; mt++)
      *(f32x4*)(slab + low * 68 + mt * 16 + quad * 4) = g[nt][mt];
    lgkm0();
    float acc = 0.f;
    int cur = lbp[nt * 16];
#pragma unroll
    for (int n = 0; n < 16; n++) {
      int b = lbp[nt * 16 + n];
      if (b != cur) {
        atomicAdd(seg + (size_t)cur * CC + wave * 64 + lane, acc);
        acc = 0.f; cur = b;
      }
      acc += slab[n * 68 + lane];
    }
    atomicAdd(seg + (size_t)cur * CC + wave * 64 + lane, acc);
    lgkm0();
  }
}

// ---- K2: seg -> seg_mean ----
__global__ __launch_bounds__(256) void k_norm(float* __restrict__ seg,
                                              const int* __restrict__ cnt) {
  int g = blockIdx.x;
  int c = cnt[g];
  float s = (c > 0) ? (1.0f / (float)c) : 0.0f;
  seg[(size_t)g * CC + threadIdx.x] *= s;
}

// ---- K3: local MLP + gather + attn MLP + sigmoid ----
__global__ __launch_bounds__(256, 4) void k_attn(
    const float* __restrict__ x, const u16* __restrict__ wbf,
    const int* __restrict__ bidx, const float* __restrict__ seg,
    const float* __restrict__ pal, const float* __restrict__ paa,
    float* __restrict__ out) {
  __shared__ __align__(16) char smem[40960];
  const int tid = threadIdx.x;
  const int wave = tid >> 6, lane = tid & 63;
  const int low = lane & 15, quad = lane >> 4;
  const int node0 = blockIdx.x << 6;
  const float al = pal[0], aa = paa[0];
  const u16* w1l = wbf + 2 * 16384;
  const u16* w2l = wbf + 3 * 16384;
  const u16* w1a = wbf + 4 * 16384;
  const u16* w2a = wbf + 5 * 16384;

  // ---- stage x -> swizzled bf16 [64][256] ----
  const float* xsrc = x + (size_t)node0 * CC;
#pragma unroll
  for (int k = 0; k < 16; k++) {
    int f = k * 1024 + tid * 4;
    f32x4 v = *(const f32x4*)(xsrc + f);
    int node = f >> 8;
    u32x2 p;
    p[0] = cvt_pk_bf16(v[0], v[1]);
    p[1] = cvt_pk_bf16(v[2], v[3]);
    *(u32x2*)(smem + SWZ(node * 512 + (f & 255) * 2, node)) = p;
  }
  __syncthreads();

  // ---- local layer1 ----
  f32x4 z[4] = {};
  const u16* w1p = w1l + (wave * 16 + low) * CC;
#pragma unroll
  for (int ks = 0; ks < 8; ks++) {
    short8 wa = *(const short8*)(w1p + ks * 32 + quad * 8);
#pragma unroll
    for (int nt = 0; nt < 4; nt++) {
      int node = nt * 16 + low;
      short8 xf = *(const short8*)(smem + SWZ(node * 512 + ks * 64 + quad * 16, node));
      z[nt] = MFMA16(wa, xf, z[nt]);
    }
  }
#pragma unroll
  for (int nt = 0; nt < 4; nt++) {
    float v0 = z[nt][0], v1 = z[nt][1], v2 = z[nt][2], v3 = z[nt][3];
    v0 = v0 >= 0.f ? v0 : al * v0;
    v1 = v1 >= 0.f ? v1 : al * v1;
    v2 = v2 >= 0.f ? v2 : al * v2;
    v3 = v3 >= 0.f ? v3 : al * v3;
    int node = nt * 16 + low;
    u32x2 p;
    p[0] = cvt_pk_bf16(v0, v1);
    p[1] = cvt_pk_bf16(v2, v3);
    *(u32x2*)(smem + ZBOFF + SWZ(node * 128 + wave * 32 + quad * 8, node)) = p;
  }
  __syncthreads();

  // ---- local layer2 -> loc[nt][mt] ----
  f32x4 loc[4][4] = {};
#pragma unroll
  for (int ks2 = 0; ks2 < 2; ks2++) {
    short8 zf[4];
#pragma unroll
    for (int nt = 0; nt < 4; nt++) {
      int node = nt * 16 + low;
      zf[nt] = *(const short8*)(smem + ZBOFF + SWZ(node * 128 + ks2 * 64 + quad * 16, node));
    }
#pragma unroll
    for (int mt = 0; mt < 4; mt++) {
      short8 wa = *(const short8*)(w2l + (wave * 64 + mt * 16 + low) * RR + ks2 * 32 + quad * 8);
#pragma unroll
      for (int nt = 0; nt < 4; nt++)
        loc[nt][mt] = MFMA16(wa, zf[nt], loc[nt][mt]);
    }
  }

  // ---- h = loc + seg_mean[bidx[node]] -> swizzled bf16 [64][256] (XB reuse) ----
  int bb[4];
#pragma unroll
  for (int nt = 0; nt < 4; nt++) bb[nt] = bidx[node0 + nt * 16 + low];
#pragma unroll
  for (int nt = 0; nt < 4; nt++) {
    const float* srow = seg + (size_t)bb[nt] * CC + wave * 64;
    int node = nt * 16 + low;
#pragma unroll
    for (int mt = 0; mt < 4; mt++) {
      f32x4 sv = *(const f32x4*)(srow + mt * 16 + quad * 4);
      u32x2 p;
      p[0] = cvt_pk_bf16(loc[nt][mt][0] + sv[0], loc[nt][mt][1] + sv[1]);
      p[1] = cvt_pk_bf16(loc[nt][mt][2] + sv[2], loc[nt][mt][3] + sv[3]);
      *(u32x2*)(smem + SWZ(node * 512 + wave * 128 + mt * 32 + quad * 8, node)) = p;
    }
  }
  __syncthreads();

  // ---- attn layer1 (B-frags from h) ----
  f32x4 z2[4] = {};
  const u16* w1pa = w1a + (wave * 16 + low) * CC;
#pragma unroll
  for (int ks = 0; ks < 8; ks++) {
    short8 wa = *(const short8*)(w1pa + ks * 32 + quad * 8);
#pragma unroll
    for (int nt = 0; nt < 4; nt++) {
      int node = nt * 16 + low;
      short8 hf = *(const short8*)(smem + SWZ(node * 512 + ks * 64 + quad * 16, node));
      z2[nt] = MFMA16(wa, hf, z2[nt]);
    }
  }
#pragma unroll
  for (int nt = 0; nt < 4; nt++) {
    float v0 = z2[nt][0], v1 = z2[nt][1], v2 = z2[nt][2], v3 = z2[nt][3];
    v0 = v0 >= 0.f ? v0 : aa * v0;
    v1 = v1 >= 0.f ? v1 : aa * v1;
    v2 = v2 >= 0.f ? v2 : aa * v2;
    v3 = v3 >= 0.f ? v3 : aa * v3;
    int node = nt * 16 + low;
    u32x2 p;
    p[0] = cvt_pk_bf16(v0, v1);
    p[1] = cvt_pk_bf16(v2, v3);
    *(u32x2*)(smem + ZBOFF + SWZ(node * 128 + wave * 32 + quad * 8, node)) = p;
  }
  __syncthreads();

  // ---- attn layer2 -> o[nt][mt] ----
  f32x4 o[4][4] = {};
#pragma unroll
  for (int ks2 = 0; ks2 < 2; ks2++) {
    short8 zf[4];
#pragma unroll
    for (int nt = 0; nt < 4; nt++) {
      int node = nt * 16 + low;
      zf[nt] = *(const short8*)(smem + ZBOFF + SWZ(node * 128 + ks2 * 64 + quad * 16, node));
    }
#pragma unroll
    for (int mt = 0; mt < 4; mt++) {
      short8 wa = *(const short8*)(w2a + (wave * 64 + mt * 16 + low) * RR + ks2 * 32 + quad * 8);
#pragma unroll
      for (int nt = 0; nt < 4; nt++)
        o[nt][mt] = MFMA16(wa, zf[nt], o[nt][mt]);
    }
  }
  // sigmoid (v_exp + v_rcp)
#pragma unroll
  for (int nt = 0; nt < 4; nt++)
#pragma unroll
    for (int mt = 0; mt < 4; mt++)
#pragma unroll
      for (int i = 0; i < 4; i++)
        o[nt][mt][i] = __builtin_amdgcn_rcpf(1.0f + __expf(-o[nt][mt][i]));
  lgkm0();

  // ---- coalesced store via per-wave [16][68] f32 slabs (XB reuse) ----
  float* slab = (float*)(smem + wave * 4352);
#pragma unroll
  for (int nt = 0; nt < 4; nt++) {
#pragma unroll
    for (int mt = 0; mt < 4; mt++)
      *(f32x4*)(slab + low * 68 + mt * 16 + quad * 4) = o[nt][mt];
    lgkm0();
#pragma unroll
    for (int n = 0; n < 16; n++)
      out[(size_t)(node0 + nt * 16 + n) * CC + wave * 64 + lane] = slab[n * 68 + lane];
    lgkm0();
  }
}

extern "C" void kernel_launch(void* const* d_in, const int* in_sizes, int n_in,
                              void* d_out, int out_size, void* d_ws, size_t ws_size,
                              hipStream_t stream) {
  (void)in_sizes; (void)n_in; (void)out_size; (void)ws_size;
  const float* x   = (const float*)d_in[0];
  const float* w1g = (const float*)d_in[1];
  const float* ag  = (const float*)d_in[2];
  const float* w2g = (const float*)d_in[3];
  const float* w1l = (const float*)d_in[4];
  const float* al  = (const float*)d_in[5];
  const float* w2l = (const float*)d_in[6];
  const float* w1a = (const float*)d_in[7];
  const float* aa  = (const float*)d_in[8];
  const float* w2a = (const float*)d_in[9];
  const int* bidx  = (const int*)d_in[10];
  float* out = (float*)d_out;

  u16* wbf   = (u16*)d_ws;
  float* seg = (float*)((char*)d_ws + 196608);
  int* cnt   = (int*)((char*)d_ws + 196608 + 1048576);

  hipMemsetAsync(seg, 0, 1048576 + 4096, stream);
  k_cvt<<<96, 256, 0, stream>>>(w1g, w2g, w1l, w2l, w1a, w2a, wbf);
  k_glb<<<NN / 64, 256, 0, stream>>>(x, wbf, bidx, ag, seg, cnt);
  k_norm<<<GG, 256, 0, stream>>>(seg, cnt);
  k_attn<<<NN / 64, 256, 0, stream>>>(x, wbf, bidx, seg, al, aa, out);
}